// Round 5
// baseline (799.343 us; speedup 1.0000x reference)
//
#include <hip/hip_runtime.h>

#define NPTS 1048576

#define DHW0 (32 * 32 * 32)
#define DHW1 (64 * 64 * 64)
#define DHW2 (128 * 128 * 128)
#define DHW3 (256 * 256 * 256)

typedef float v4f __attribute__((ext_vector_type(4)));

// ---------------- math helpers ----------------

__device__ __forceinline__ float4 lerp4(const float4 a, const float4 b, const float t) {
    return make_float4(a.x + (b.x - a.x) * t,
                       a.y + (b.y - a.y) * t,
                       a.z + (b.z - a.z) * t,
                       a.w + (b.w - a.w) * t);
}

struct CoordW { float tx, ty, tz; int b00, b01, b10, b11, x0, x1; };

template<int D>
__device__ __forceinline__ CoordW mkcoord(float gx, float gy, float gz) {
    CoordW c;
    float x = fminf(fmaxf((gx + 1.0f) * (0.5f * (float)(D - 1)), 0.0f), (float)(D - 1));
    float y = fminf(fmaxf((gy + 1.0f) * (0.5f * (float)(D - 1)), 0.0f), (float)(D - 1));
    float z = fminf(fmaxf((gz + 1.0f) * (0.5f * (float)(D - 1)), 0.0f), (float)(D - 1));
    float xf = floorf(x), yf = floorf(y), zf = floorf(z);
    float tx = x - xf, ty = y - yf, tz = z - zf;
    c.tx = tx * tx * (3.0f - 2.0f * tx);
    c.ty = ty * ty * (3.0f - 2.0f * ty);
    c.tz = tz * tz * (3.0f - 2.0f * tz);
    int x0 = (int)xf, y0 = (int)yf, z0 = (int)zf;
    int y1 = min(y0 + 1, D - 1), z1 = min(z0 + 1, D - 1);
    c.x0 = x0;
    c.x1 = min(x0 + 1, D - 1);
    c.b00 = (z0 * D + y0) * D;
    c.b01 = (z0 * D + y1) * D;
    c.b10 = (z1 * D + y0) * D;
    c.b11 = (z1 * D + y1) * D;
    return c;
}

__device__ __forceinline__ float4 reduce8(const float4* q, const CoordW& c) {
    float4 c00 = lerp4(q[0], q[1], c.tx);
    float4 c01 = lerp4(q[2], q[3], c.tx);
    float4 c10 = lerp4(q[4], q[5], c.tx);
    float4 c11 = lerp4(q[6], q[7], c.tx);
    float4 c0 = lerp4(c00, c01, c.ty);
    float4 c1 = lerp4(c10, c11, c.ty);
    return lerp4(c0, c1, c.tz);
}

// trilinear for the native-layout 256^3 volume from 16 float2 row-pairs
__device__ __forceinline__ float4 reduce_v3(const float2* qd, const CoordW& c, bool edge) {
    float r[4];
#pragma unroll
    for (int ch = 0; ch < 4; ++ch) {
        float v00a = edge ? qd[ch * 4 + 0].y : qd[ch * 4 + 0].x, v00b = qd[ch * 4 + 0].y;
        float v01a = edge ? qd[ch * 4 + 1].y : qd[ch * 4 + 1].x, v01b = qd[ch * 4 + 1].y;
        float v10a = edge ? qd[ch * 4 + 2].y : qd[ch * 4 + 2].x, v10b = qd[ch * 4 + 2].y;
        float v11a = edge ? qd[ch * 4 + 3].y : qd[ch * 4 + 3].x, v11b = qd[ch * 4 + 3].y;
        float c00 = v00a + (v00b - v00a) * c.tx;
        float c01 = v01a + (v01b - v01a) * c.tx;
        float c10 = v10a + (v10b - v10a) * c.tx;
        float c11 = v11a + (v11b - v11a) * c.tx;
        float e0 = c00 + (c01 - c00) * c.ty;
        float e1 = c10 + (c11 - c10) * c.ty;
        r[ch] = e0 + (e1 - e0) * c.tz;
    }
    return make_float4(r[0], r[1], r[2], r[3]);
}

// 8-stream coalesced NT store (consecutive p across lanes -> full lines)
__device__ __forceinline__ void store8(const float4 fa, const float4 fb,
                                       float* __restrict__ out, int p) {
    __builtin_nontemporal_store(fa.x, &out[0 * NPTS + p]);
    __builtin_nontemporal_store(fa.y, &out[1 * NPTS + p]);
    __builtin_nontemporal_store(fa.z, &out[2 * NPTS + p]);
    __builtin_nontemporal_store(fa.w, &out[3 * NPTS + p]);
    __builtin_nontemporal_store(fb.x, &out[4 * NPTS + p]);
    __builtin_nontemporal_store(fb.y, &out[5 * NPTS + p]);
    __builtin_nontemporal_store(fb.z, &out[6 * NPTS + p]);
    __builtin_nontemporal_store(fb.w, &out[7 * NPTS + p]);
}

__device__ __forceinline__ void store16(const float4 f0, const float4 f1,
                                        const float4 f2, const float4 f3,
                                        float* __restrict__ out, int p) {
    store8(f0, f1, out, p);
    store8(f2, f3, out + 8 * NPTS, p);
}

// ---------------- transpose [C,DHW] -> [DHW,C] for the 3 small volumes ----------------

__global__ __launch_bounds__(256) void xpose_kernel(
    const float* __restrict__ v0, const float* __restrict__ v1,
    const float* __restrict__ v2,
    float4* __restrict__ w0, float4* __restrict__ w1, float4* __restrict__ w2)
{
    constexpr int B2 = DHW2 / 256, B1 = DHW1 / 256;
    int b = blockIdx.x;
    int t = threadIdx.x;
    if (b < B2) {
        int v = b * 256 + t;
        w2[v] = make_float4(v2[v], v2[v + DHW2], v2[v + 2 * DHW2], v2[v + 3 * DHW2]);
    } else if (b < B2 + B1) {
        int v = (b - B2) * 256 + t;
        w1[v] = make_float4(v1[v], v1[v + DHW1], v1[v + 2 * DHW1], v1[v + 3 * DHW1]);
    } else {
        int v = (b - B2 - B1) * 256 + t;
        w0[v] = make_float4(v0[v], v0[v + DHW0], v0[v + 2 * DHW0], v0[v + 3 * DHW0]);
    }
}

// ---------------- split main kernels (original point order, no sort) ----------------
// Volume-split so each kernel's live load-result set (~64 VGPR) fits without
// the RA serializing it (rounds 0-3 all showed VGPR 52-80 << the ~130-160 a
// 40-load batch needs -> the "issue everything" structure never materialized).
// Concurrency now comes from waves (high occupancy, small live set), not from
// one mega ILP batch.

// f0+f1 from w0+w1 (4.5 MB total -> L2/LLC resident after warm-up).
__global__ __launch_bounds__(256, 4) void mg_small_kernel(
    const float* __restrict__ grid,
    const float4* __restrict__ w0, const float4* __restrict__ w1,
    float* __restrict__ out)
{
    int p = blockIdx.x * 256 + (int)threadIdx.x;
    float gx = grid[3 * p + 0];
    float gy = grid[3 * p + 1];
    float gz = grid[3 * p + 2];

    CoordW c0 = mkcoord<32>(gx, gy, gz);
    CoordW c1 = mkcoord<64>(gx, gy, gz);

    float4 qa[8], qb[8];
    qa[0] = w0[c0.b00 + c0.x0]; qa[1] = w0[c0.b00 + c0.x1];
    qa[2] = w0[c0.b01 + c0.x0]; qa[3] = w0[c0.b01 + c0.x1];
    qa[4] = w0[c0.b10 + c0.x0]; qa[5] = w0[c0.b10 + c0.x1];
    qa[6] = w0[c0.b11 + c0.x0]; qa[7] = w0[c0.b11 + c0.x1];

    qb[0] = w1[c1.b00 + c1.x0]; qb[1] = w1[c1.b00 + c1.x1];
    qb[2] = w1[c1.b01 + c1.x0]; qb[3] = w1[c1.b01 + c1.x1];
    qb[4] = w1[c1.b10 + c1.x0]; qb[5] = w1[c1.b10 + c1.x1];
    qb[6] = w1[c1.b11 + c1.x0]; qb[7] = w1[c1.b11 + c1.x1];

    __builtin_amdgcn_sched_barrier(0);

    float4 f0 = reduce8(qa, c0);
    float4 f1 = reduce8(qb, c1);
    store8(f0, f1, out, p);
}

// f2+f3 from w2 (32 MB -> L3) + native v3 (256 MB, LLC-sized; random touches
// mostly L3-hit after first touch since avg line reuse ~3.8x).
__global__ __launch_bounds__(256, 4) void mg_big_kernel(
    const float* __restrict__ grid,
    const float4* __restrict__ w2, const float* __restrict__ v3,
    float* __restrict__ out)
{
    int p = blockIdx.x * 256 + (int)threadIdx.x;
    float gx = grid[3 * p + 0];
    float gy = grid[3 * p + 1];
    float gz = grid[3 * p + 2];

    CoordW c2 = mkcoord<128>(gx, gy, gz);
    CoordW c3 = mkcoord<256>(gx, gy, gz);
    const int  xm = min(c3.x0, 254);
    const bool edge = (c3.x0 == 255);

    float4 qc[8];
    float2 qd[16];

    // issue order == consume order (FIFO vmcnt): w2 first, v3 last
    qc[0] = w2[c2.b00 + c2.x0]; qc[1] = w2[c2.b00 + c2.x1];
    qc[2] = w2[c2.b01 + c2.x0]; qc[3] = w2[c2.b01 + c2.x1];
    qc[4] = w2[c2.b10 + c2.x0]; qc[5] = w2[c2.b10 + c2.x1];
    qc[6] = w2[c2.b11 + c2.x0]; qc[7] = w2[c2.b11 + c2.x1];

#pragma unroll
    for (int ch = 0; ch < 4; ++ch) {
        const float* __restrict__ vc = v3 + (size_t)ch * DHW3;
        qd[ch * 4 + 0] = *(const float2*)(vc + c3.b00 + xm);
        qd[ch * 4 + 1] = *(const float2*)(vc + c3.b01 + xm);
        qd[ch * 4 + 2] = *(const float2*)(vc + c3.b10 + xm);
        qd[ch * 4 + 3] = *(const float2*)(vc + c3.b11 + xm);
    }

    __builtin_amdgcn_sched_barrier(0);

    float4 f2 = reduce8(qc, c2);
    float4 f3 = reduce_v3(qd, c3, edge);
    store8(f2, f3, out + 8 * NPTS, p);
}

// ---------------- no-workspace fallback ----------------

template<int D>
__device__ __forceinline__ float4 sample_direct(const float* __restrict__ v,
                                                float gx, float gy, float gz) {
    CoordW c = mkcoord<D>(gx, gy, gz);
    float r[4];
#pragma unroll
    for (int ch = 0; ch < 4; ++ch) {
        const float* __restrict__ vc = v + (size_t)ch * (D * D * D);
        float c000 = vc[c.b00 + c.x0], c001 = vc[c.b00 + c.x1];
        float c010 = vc[c.b01 + c.x0], c011 = vc[c.b01 + c.x1];
        float c100 = vc[c.b10 + c.x0], c101 = vc[c.b10 + c.x1];
        float c110 = vc[c.b11 + c.x0], c111 = vc[c.b11 + c.x1];
        float c00 = c000 + (c001 - c000) * c.tx;
        float c01 = c010 + (c011 - c010) * c.tx;
        float c10 = c100 + (c101 - c100) * c.tx;
        float c11 = c110 + (c111 - c110) * c.tx;
        float e0 = c00 + (c01 - c00) * c.ty;
        float e1 = c10 + (c11 - c10) * c.ty;
        r[ch] = e0 + (e1 - e0) * c.tz;
    }
    return make_float4(r[0], r[1], r[2], r[3]);
}

__global__ __launch_bounds__(256) void mg_direct_kernel(
    const float* __restrict__ grid,
    const float* __restrict__ v0, const float* __restrict__ v1,
    const float* __restrict__ v2, const float* __restrict__ v3,
    float* __restrict__ out)
{
    int p = blockIdx.x * blockDim.x + threadIdx.x;
    float gx = grid[3 * p + 0];
    float gy = grid[3 * p + 1];
    float gz = grid[3 * p + 2];
    float4 f0 = sample_direct<32>(v0, gx, gy, gz);
    float4 f1 = sample_direct<64>(v1, gx, gy, gz);
    float4 f2 = sample_direct<128>(v2, gx, gy, gz);
    float4 f3 = sample_direct<256>(v3, gx, gy, gz);
    store16(f0, f1, f2, f3, out, p);
}

// ---------------- launch ----------------

extern "C" void kernel_launch(void* const* d_in, const int* in_sizes, int n_in,
                              void* d_out, int out_size, void* d_ws, size_t ws_size,
                              hipStream_t stream) {
    const float* grid = (const float*)d_in[0];
    const float* v0   = (const float*)d_in[1];   // [4,32,32,32]
    const float* v1   = (const float*)d_in[2];   // [4,64,64,64]
    const float* v2   = (const float*)d_in[3];   // [4,128,128,128]
    const float* v3   = (const float*)d_in[4];   // [4,256,256,256]
    float* out = (float*)d_out;

    constexpr size_t WS_INTER = (size_t)(DHW0 + DHW1 + DHW2) * 16;   // 36.5 MB

    const int threads = 256;
    const int pt_blocks = NPTS / threads;                  // 4096
    constexpr int xb_small = (DHW0 + DHW1 + DHW2) / 256;   // 9344

    if (ws_size >= WS_INTER) {
        float4* w0 = (float4*)d_ws;
        float4* w1 = w0 + DHW0;
        float4* w2 = w1 + DHW1;
        xpose_kernel<<<xb_small, threads, 0, stream>>>(v0, v1, v2, w0, w1, w2);
        mg_big_kernel<<<pt_blocks, threads, 0, stream>>>(grid, w2, v3, out);
        mg_small_kernel<<<pt_blocks, threads, 0, stream>>>(grid, w0, w1, out);
    } else {
        mg_direct_kernel<<<pt_blocks, threads, 0, stream>>>(grid, v0, v1, v2, v3, out);
    }
}

// Round 7
// 743.468 us; speedup vs baseline: 1.0752x; 1.0752x over previous
//
#include <hip/hip_runtime.h>

#define NPTS 1048576
#define NB 32
#define NBINS (NB * NB * NB)   // 32768

#define DHW0 (32 * 32 * 32)
#define DHW1 (64 * 64 * 64)
#define DHW2 (128 * 128 * 128)
#define DHW3 (256 * 256 * 256)

typedef float v4f __attribute__((ext_vector_type(4)));

__device__ __forceinline__ void nt_store4(const float4 f, float4* p) {
    __builtin_nontemporal_store(*(const v4f*)&f, (v4f*)p);
}

// ---------------- math helpers ----------------

__device__ __forceinline__ float4 lerp4(const float4 a, const float4 b, const float t) {
    return make_float4(a.x + (b.x - a.x) * t,
                       a.y + (b.y - a.y) * t,
                       a.z + (b.z - a.z) * t,
                       a.w + (b.w - a.w) * t);
}

struct CoordW { float tx, ty, tz; int b00, b01, b10, b11, x0, x1; };

template<int D>
__device__ __forceinline__ CoordW mkcoord(float gx, float gy, float gz) {
    CoordW c;
    float x = fminf(fmaxf((gx + 1.0f) * (0.5f * (float)(D - 1)), 0.0f), (float)(D - 1));
    float y = fminf(fmaxf((gy + 1.0f) * (0.5f * (float)(D - 1)), 0.0f), (float)(D - 1));
    float z = fminf(fmaxf((gz + 1.0f) * (0.5f * (float)(D - 1)), 0.0f), (float)(D - 1));
    float xf = floorf(x), yf = floorf(y), zf = floorf(z);
    float tx = x - xf, ty = y - yf, tz = z - zf;
    c.tx = tx * tx * (3.0f - 2.0f * tx);
    c.ty = ty * ty * (3.0f - 2.0f * ty);
    c.tz = tz * tz * (3.0f - 2.0f * tz);
    int x0 = (int)xf, y0 = (int)yf, z0 = (int)zf;
    int y1 = min(y0 + 1, D - 1), z1 = min(z0 + 1, D - 1);
    c.x0 = x0;
    c.x1 = min(x0 + 1, D - 1);
    c.b00 = (z0 * D + y0) * D;
    c.b01 = (z0 * D + y1) * D;
    c.b10 = (z1 * D + y0) * D;
    c.b11 = (z1 * D + y1) * D;
    return c;
}

__device__ __forceinline__ float4 reduce8(const float4* q, const CoordW& c) {
    float4 c00 = lerp4(q[0], q[1], c.tx);
    float4 c01 = lerp4(q[2], q[3], c.tx);
    float4 c10 = lerp4(q[4], q[5], c.tx);
    float4 c11 = lerp4(q[6], q[7], c.tx);
    float4 c0 = lerp4(c00, c01, c.ty);
    float4 c1 = lerp4(c10, c11, c.ty);
    return lerp4(c0, c1, c.tz);
}

// trilinear for the native-layout 256^3 volume from 16 float2 row-pairs
__device__ __forceinline__ float4 reduce_v3(const float2* qd, const CoordW& c, bool edge) {
    float r[4];
#pragma unroll
    for (int ch = 0; ch < 4; ++ch) {
        float v00a = edge ? qd[ch * 4 + 0].y : qd[ch * 4 + 0].x, v00b = qd[ch * 4 + 0].y;
        float v01a = edge ? qd[ch * 4 + 1].y : qd[ch * 4 + 1].x, v01b = qd[ch * 4 + 1].y;
        float v10a = edge ? qd[ch * 4 + 2].y : qd[ch * 4 + 2].x, v10b = qd[ch * 4 + 2].y;
        float v11a = edge ? qd[ch * 4 + 3].y : qd[ch * 4 + 3].x, v11b = qd[ch * 4 + 3].y;
        float c00 = v00a + (v00b - v00a) * c.tx;
        float c01 = v01a + (v01b - v01a) * c.tx;
        float c10 = v10a + (v10b - v10a) * c.tx;
        float c11 = v11a + (v11b - v11a) * c.tx;
        float e0 = c00 + (c01 - c00) * c.ty;
        float e1 = c10 + (c11 - c10) * c.ty;
        r[ch] = e0 + (e1 - e0) * c.tz;
    }
    return make_float4(r[0], r[1], r[2], r[3]);
}

// ---------------- binning ----------------

__device__ __forceinline__ int bin_of(float gx, float gy, float gz) {
    float ux = fminf(fmaxf((gx + 1.0f) * 0.5f, 0.0f), 1.0f);
    float uy = fminf(fmaxf((gy + 1.0f) * 0.5f, 0.0f), 1.0f);
    float uz = fminf(fmaxf((gz + 1.0f) * 0.5f, 0.0f), 1.0f);
    int bx = min((int)(ux * (float)NB), NB - 1);
    int by = min((int)(uy * (float)NB), NB - 1);
    int bz = min((int)(uz * (float)NB), NB - 1);
    return (bz * NB + by) * NB + bx;
}

// ---------------- fused transpose [C,DHW]->[DHW,C] (3 vols) + histogram ----------------

__global__ __launch_bounds__(256) void xpose_hist_kernel(
    const float* __restrict__ v0, const float* __restrict__ v1, const float* __restrict__ v2,
    float4* __restrict__ w0, float4* __restrict__ w1, float4* __restrict__ w2,
    const float* __restrict__ grid, unsigned* __restrict__ hist)
{
    constexpr int B2 = DHW2 / 256, B1 = DHW1 / 256, B0 = DHW0 / 256;
    int b = blockIdx.x;
    int t = threadIdx.x;
    if (b < B2) {
        int v = b * 256 + t;
        w2[v] = make_float4(v2[v], v2[v + DHW2], v2[v + 2 * DHW2], v2[v + 3 * DHW2]);
    } else if (b < B2 + B1) {
        int v = (b - B2) * 256 + t;
        w1[v] = make_float4(v1[v], v1[v + DHW1], v1[v + 2 * DHW1], v1[v + 3 * DHW1]);
    } else if (b < B2 + B1 + B0) {
        int v = (b - B2 - B1) * 256 + t;
        w0[v] = make_float4(v0[v], v0[v + DHW0], v0[v + 2 * DHW0], v0[v + 3 * DHW0]);
    } else {
        int p = (b - B2 - B1 - B0) * 256 + t;
        float gx = grid[3 * p + 0];
        float gy = grid[3 * p + 1];
        float gz = grid[3 * p + 2];
        atomicAdd(&hist[bin_of(gx, gy, gz)], 1u);
    }
}

// single-workgroup exclusive scan of NBINS=32768 counts (1024 thr x 32 items)
__global__ __launch_bounds__(1024) void scan_kernel(const unsigned* __restrict__ hist,
                                                    unsigned* __restrict__ offsets) {
    __shared__ unsigned partial[1024];
    const int t = threadIdx.x;
    const int base = t * 32;
    unsigned sum = 0;
#pragma unroll
    for (int i = 0; i < 32; ++i) sum += hist[base + i];
    partial[t] = sum;
    __syncthreads();
    for (int off = 1; off < 1024; off <<= 1) {
        unsigned v = (t >= off) ? partial[t - off] : 0u;
        __syncthreads();
        partial[t] += v;
        __syncthreads();
    }
    unsigned run = partial[t] - sum;
#pragma unroll
    for (int i = 0; i < 32; ++i) {
        offsets[base + i] = run;
        run += hist[base + i];
    }
}

// scatter: sorted[pos] = (gx,gy,gz, origP). No inv[] — the reordering back to
// original order happens on gather's WRITE side (scattered full-line writes
// don't stall; the old permute's scattered READS did).
__global__ __launch_bounds__(256) void scatter_kernel(const float* __restrict__ grid,
                                                      unsigned* __restrict__ offsets,
                                                      float4* __restrict__ sorted) {
    int p = blockIdx.x * blockDim.x + threadIdx.x;
    float gx = grid[3 * p + 0];
    float gy = grid[3 * p + 1];
    float gz = grid[3 * p + 2];
    int b = bin_of(gx, gy, gz);
    unsigned pos = atomicAdd(&offsets[b], 1u);
    sorted[pos] = make_float4(gx, gy, gz, __int_as_float(p));
}

// ---------------- main gather over sorted points (R1 1-pt/thread body) ----------------
// 40 loads issued before any arithmetic (issue order == consume order, v3 last
// so FIFO vmcnt lets f0..f2 math run while v3/HBM loads are in flight).
// Output: 64B (4x float4, line-aligned) NT-stored to wsout[origP] — scattered
// across lines but each write is a FULL line -> write-combines, and stores are
// fire-and-forget (no latency stall), unlike the old permute's scattered reads.

__global__ __launch_bounds__(256, 3) void gather_sorted_kernel(
    const float4* __restrict__ sorted,
    const float4* __restrict__ w0, const float4* __restrict__ w1,
    const float4* __restrict__ w2, const float* __restrict__ v3,
    float4* __restrict__ wsout)
{
    // XCD swizzle: contiguous sorted range per XCD for L2 locality
    int bid = blockIdx.x;
    int sb = (bid & 7) * (int)(gridDim.x >> 3) + (bid >> 3);
    int s = sb * 256 + (int)threadIdx.x;
    float4 gp = sorted[s];
    float gx = gp.x, gy = gp.y, gz = gp.z;
    int origP = __float_as_int(gp.w);

    CoordW c0 = mkcoord<32>(gx, gy, gz);
    CoordW c1 = mkcoord<64>(gx, gy, gz);
    CoordW c2 = mkcoord<128>(gx, gy, gz);
    CoordW c3 = mkcoord<256>(gx, gy, gz);
    const int  xm = min(c3.x0, 254);
    const bool edge = (c3.x0 == 255);

    float4 qa[8], qb[8], qc[8];
    float2 qd[16];

    qa[0] = w0[c0.b00 + c0.x0]; qa[1] = w0[c0.b00 + c0.x1];
    qa[2] = w0[c0.b01 + c0.x0]; qa[3] = w0[c0.b01 + c0.x1];
    qa[4] = w0[c0.b10 + c0.x0]; qa[5] = w0[c0.b10 + c0.x1];
    qa[6] = w0[c0.b11 + c0.x0]; qa[7] = w0[c0.b11 + c0.x1];

    qb[0] = w1[c1.b00 + c1.x0]; qb[1] = w1[c1.b00 + c1.x1];
    qb[2] = w1[c1.b01 + c1.x0]; qb[3] = w1[c1.b01 + c1.x1];
    qb[4] = w1[c1.b10 + c1.x0]; qb[5] = w1[c1.b10 + c1.x1];
    qb[6] = w1[c1.b11 + c1.x0]; qb[7] = w1[c1.b11 + c1.x1];

    qc[0] = w2[c2.b00 + c2.x0]; qc[1] = w2[c2.b00 + c2.x1];
    qc[2] = w2[c2.b01 + c2.x0]; qc[3] = w2[c2.b01 + c2.x1];
    qc[4] = w2[c2.b10 + c2.x0]; qc[5] = w2[c2.b10 + c2.x1];
    qc[6] = w2[c2.b11 + c2.x0]; qc[7] = w2[c2.b11 + c2.x1];

#pragma unroll
    for (int ch = 0; ch < 4; ++ch) {
        const float* __restrict__ vc = v3 + (size_t)ch * DHW3;
        qd[ch * 4 + 0] = *(const float2*)(vc + c3.b00 + xm);
        qd[ch * 4 + 1] = *(const float2*)(vc + c3.b01 + xm);
        qd[ch * 4 + 2] = *(const float2*)(vc + c3.b10 + xm);
        qd[ch * 4 + 3] = *(const float2*)(vc + c3.b11 + xm);
    }

    __builtin_amdgcn_sched_barrier(0);

    float4 f0 = reduce8(qa, c0);
    float4 f1 = reduce8(qb, c1);
    float4 f2 = reduce8(qc, c2);
    float4 f3 = reduce_v3(qd, c3, edge);

    float4* w = wsout + (size_t)origP * 4;
    nt_store4(f0, w + 0);
    nt_store4(f1, w + 1);
    nt_store4(f2, w + 2);
    nt_store4(f3, w + 3);
}

// ---------------- unpermute: pure streaming pass, fully coalesced both sides --------
// read wsout[p][0..3] (contiguous 64B/thread, wave reads 16KB linear), write
// the 16 SoA output streams (consecutive p across lanes -> full lines).

__global__ __launch_bounds__(256) void unpermute_kernel(const float4* __restrict__ wsout,
                                                        float* __restrict__ out) {
    int p = blockIdx.x * blockDim.x + threadIdx.x;
    const float4* w = wsout + (size_t)p * 4;
    float4 f0 = w[0], f1 = w[1], f2 = w[2], f3 = w[3];
    __builtin_nontemporal_store(f0.x, &out[ 0 * NPTS + p]);
    __builtin_nontemporal_store(f0.y, &out[ 1 * NPTS + p]);
    __builtin_nontemporal_store(f0.z, &out[ 2 * NPTS + p]);
    __builtin_nontemporal_store(f0.w, &out[ 3 * NPTS + p]);
    __builtin_nontemporal_store(f1.x, &out[ 4 * NPTS + p]);
    __builtin_nontemporal_store(f1.y, &out[ 5 * NPTS + p]);
    __builtin_nontemporal_store(f1.z, &out[ 6 * NPTS + p]);
    __builtin_nontemporal_store(f1.w, &out[ 7 * NPTS + p]);
    __builtin_nontemporal_store(f2.x, &out[ 8 * NPTS + p]);
    __builtin_nontemporal_store(f2.y, &out[ 9 * NPTS + p]);
    __builtin_nontemporal_store(f2.z, &out[10 * NPTS + p]);
    __builtin_nontemporal_store(f2.w, &out[11 * NPTS + p]);
    __builtin_nontemporal_store(f3.x, &out[12 * NPTS + p]);
    __builtin_nontemporal_store(f3.y, &out[13 * NPTS + p]);
    __builtin_nontemporal_store(f3.z, &out[14 * NPTS + p]);
    __builtin_nontemporal_store(f3.w, &out[15 * NPTS + p]);
}

// ---------------- fallback paths ----------------

template<int D>
__device__ __forceinline__ float4 sample_inter(const float4* __restrict__ v,
                                               float gx, float gy, float gz) {
    CoordW c = mkcoord<D>(gx, gy, gz);
    float4 q[8];
    q[0] = v[c.b00 + c.x0]; q[1] = v[c.b00 + c.x1];
    q[2] = v[c.b01 + c.x0]; q[3] = v[c.b01 + c.x1];
    q[4] = v[c.b10 + c.x0]; q[5] = v[c.b10 + c.x1];
    q[6] = v[c.b11 + c.x0]; q[7] = v[c.b11 + c.x1];
    return reduce8(q, c);
}

template<int D>
__device__ __forceinline__ float4 sample_direct(const float* __restrict__ v,
                                                float gx, float gy, float gz) {
    CoordW c = mkcoord<D>(gx, gy, gz);
    float r[4];
#pragma unroll
    for (int ch = 0; ch < 4; ++ch) {
        const float* __restrict__ vc = v + (size_t)ch * (D * D * D);
        float c000 = vc[c.b00 + c.x0], c001 = vc[c.b00 + c.x1];
        float c010 = vc[c.b01 + c.x0], c011 = vc[c.b01 + c.x1];
        float c100 = vc[c.b10 + c.x0], c101 = vc[c.b10 + c.x1];
        float c110 = vc[c.b11 + c.x0], c111 = vc[c.b11 + c.x1];
        float c00 = c000 + (c001 - c000) * c.tx;
        float c01 = c010 + (c011 - c010) * c.tx;
        float c10 = c100 + (c101 - c100) * c.tx;
        float c11 = c110 + (c111 - c110) * c.tx;
        float e0 = c00 + (c01 - c00) * c.ty;
        float e1 = c10 + (c11 - c10) * c.ty;
        r[ch] = e0 + (e1 - e0) * c.tz;
    }
    return make_float4(r[0], r[1], r[2], r[3]);
}

__device__ __forceinline__ void store16(const float4 f0, const float4 f1,
                                        const float4 f2, const float4 f3,
                                        float* __restrict__ out, int p) {
    out[ 0 * NPTS + p] = f0.x; out[ 1 * NPTS + p] = f0.y;
    out[ 2 * NPTS + p] = f0.z; out[ 3 * NPTS + p] = f0.w;
    out[ 4 * NPTS + p] = f1.x; out[ 5 * NPTS + p] = f1.y;
    out[ 6 * NPTS + p] = f1.z; out[ 7 * NPTS + p] = f1.w;
    out[ 8 * NPTS + p] = f2.x; out[ 9 * NPTS + p] = f2.y;
    out[10 * NPTS + p] = f2.z; out[11 * NPTS + p] = f2.w;
    out[12 * NPTS + p] = f3.x; out[13 * NPTS + p] = f3.y;
    out[14 * NPTS + p] = f3.z; out[15 * NPTS + p] = f3.w;
}

__global__ __launch_bounds__(256) void mg_direct_kernel(
    const float* __restrict__ grid,
    const float* __restrict__ v0, const float* __restrict__ v1,
    const float* __restrict__ v2, const float* __restrict__ v3,
    float* __restrict__ out)
{
    int p = blockIdx.x * blockDim.x + threadIdx.x;
    float gx = grid[3 * p + 0];
    float gy = grid[3 * p + 1];
    float gz = grid[3 * p + 2];
    float4 f0 = sample_direct<32>(v0, gx, gy, gz);
    float4 f1 = sample_direct<64>(v1, gx, gy, gz);
    float4 f2 = sample_direct<128>(v2, gx, gy, gz);
    float4 f3 = sample_direct<256>(v3, gx, gy, gz);
    store16(f0, f1, f2, f3, out, p);
}

__global__ __launch_bounds__(256) void mg_inter_kernel(
    const float* __restrict__ grid,
    const float4* __restrict__ w0, const float4* __restrict__ w1,
    const float4* __restrict__ w2, const float* __restrict__ v3,
    float* __restrict__ out)
{
    int p = blockIdx.x * blockDim.x + threadIdx.x;
    float gx = grid[3 * p + 0];
    float gy = grid[3 * p + 1];
    float gz = grid[3 * p + 2];
    float4 f0 = sample_inter<32>(w0, gx, gy, gz);
    float4 f1 = sample_inter<64>(w1, gx, gy, gz);
    float4 f2 = sample_inter<128>(w2, gx, gy, gz);
    float4 f3 = sample_direct<256>(v3, gx, gy, gz);
    store16(f0, f1, f2, f3, out, p);
}

// ---------------- launch ----------------

extern "C" void kernel_launch(void* const* d_in, const int* in_sizes, int n_in,
                              void* d_out, int out_size, void* d_ws, size_t ws_size,
                              hipStream_t stream) {
    const float* grid = (const float*)d_in[0];
    const float* v0   = (const float*)d_in[1];   // [4,32,32,32]
    const float* v1   = (const float*)d_in[2];   // [4,64,64,64]
    const float* v2   = (const float*)d_in[3];   // [4,128,128,128]
    const float* v3   = (const float*)d_in[4];   // [4,256,256,256]
    float* out = (float*)d_out;

    // ws layout (bytes)
    constexpr size_t OFF_WSOUT  = 0;                                   // 64 MB (AoS [p][4] float4)
    constexpr size_t OFF_SORTED = OFF_WSOUT  + (size_t)NPTS * 64;      // 16 MB
    constexpr size_t OFF_W2     = OFF_SORTED + (size_t)NPTS * 16;      // 32 MB
    constexpr size_t OFF_W1     = OFF_W2     + (size_t)DHW2 * 16;      // 4 MB
    constexpr size_t OFF_W0     = OFF_W1     + (size_t)DHW1 * 16;      // 0.5 MB
    constexpr size_t OFF_HIST   = OFF_W0     + (size_t)DHW0 * 16;      // 128 KB
    constexpr size_t OFF_OFFS   = OFF_HIST   + (size_t)NBINS * 4;      // 128 KB
    constexpr size_t WS_FULL    = OFF_OFFS   + (size_t)NBINS * 4;      // ~116.8 MB
    constexpr size_t WS_INTER   = (size_t)(DHW0 + DHW1 + DHW2) * 16;   // 36.5 MB

    const int threads = 256;
    const int pt_blocks = NPTS / threads;   // 4096
    char* ws = (char*)d_ws;

    if (ws_size >= WS_FULL) {
        float4*   wsout  = (float4*)(ws + OFF_WSOUT);
        float4*   sorted = (float4*)(ws + OFF_SORTED);
        float4*   w2     = (float4*)(ws + OFF_W2);
        float4*   w1     = (float4*)(ws + OFF_W1);
        float4*   w0     = (float4*)(ws + OFF_W0);
        unsigned* hist   = (unsigned*)(ws + OFF_HIST);
        unsigned* offs   = (unsigned*)(ws + OFF_OFFS);

        (void)hipMemsetAsync(hist, 0, (size_t)NBINS * 4, stream);
        const int xh_blocks = (DHW0 + DHW1 + DHW2) / threads + pt_blocks;
        xpose_hist_kernel<<<xh_blocks, threads, 0, stream>>>(
            v0, v1, v2, w0, w1, w2, grid, hist);
        scan_kernel<<<1, 1024, 0, stream>>>(hist, offs);
        scatter_kernel<<<pt_blocks, threads, 0, stream>>>(grid, offs, sorted);
        gather_sorted_kernel<<<pt_blocks, threads, 0, stream>>>(
            sorted, w0, w1, w2, v3, wsout);
        unpermute_kernel<<<pt_blocks, threads, 0, stream>>>(wsout, out);
    } else if (ws_size >= WS_INTER) {
        float4* w0 = (float4*)d_ws;
        float4* w1 = w0 + DHW0;
        float4* w2 = w1 + DHW1;
        xpose_hist_kernel<<<(DHW0 + DHW1 + DHW2) / threads, threads, 0, stream>>>(
            v0, v1, v2, w0, w1, w2, grid, (unsigned*)nullptr);
        mg_inter_kernel<<<pt_blocks, threads, 0, stream>>>(grid, w0, w1, w2, v3, out);
    } else {
        mg_direct_kernel<<<pt_blocks, threads, 0, stream>>>(grid, v0, v1, v2, v3, out);
    }
}

// Round 8
// 669.324 us; speedup vs baseline: 1.1943x; 1.1108x over previous
//
#include <hip/hip_runtime.h>

#define NPTS 1048576
#define NB 32
#define NBINS (NB * NB * NB)   // 32768

#define DHW0 (32 * 32 * 32)
#define DHW1 (64 * 64 * 64)
#define DHW2 (128 * 128 * 128)
#define DHW3 (256 * 256 * 256)

typedef float v4f __attribute__((ext_vector_type(4)));

// ---------------- math helpers ----------------

__device__ __forceinline__ float4 lerp4(const float4 a, const float4 b, const float t) {
    return make_float4(a.x + (b.x - a.x) * t,
                       a.y + (b.y - a.y) * t,
                       a.z + (b.z - a.z) * t,
                       a.w + (b.w - a.w) * t);
}

struct CoordW { float tx, ty, tz; int b00, b01, b10, b11, x0, x1; };

template<int D>
__device__ __forceinline__ CoordW mkcoord(float gx, float gy, float gz) {
    CoordW c;
    float x = fminf(fmaxf((gx + 1.0f) * (0.5f * (float)(D - 1)), 0.0f), (float)(D - 1));
    float y = fminf(fmaxf((gy + 1.0f) * (0.5f * (float)(D - 1)), 0.0f), (float)(D - 1));
    float z = fminf(fmaxf((gz + 1.0f) * (0.5f * (float)(D - 1)), 0.0f), (float)(D - 1));
    float xf = floorf(x), yf = floorf(y), zf = floorf(z);
    float tx = x - xf, ty = y - yf, tz = z - zf;
    c.tx = tx * tx * (3.0f - 2.0f * tx);
    c.ty = ty * ty * (3.0f - 2.0f * ty);
    c.tz = tz * tz * (3.0f - 2.0f * tz);
    int x0 = (int)xf, y0 = (int)yf, z0 = (int)zf;
    int y1 = min(y0 + 1, D - 1), z1 = min(z0 + 1, D - 1);
    c.x0 = x0;
    c.x1 = min(x0 + 1, D - 1);
    c.b00 = (z0 * D + y0) * D;
    c.b01 = (z0 * D + y1) * D;
    c.b10 = (z1 * D + y0) * D;
    c.b11 = (z1 * D + y1) * D;
    return c;
}

__device__ __forceinline__ float4 reduce8(const float4* q, const CoordW& c) {
    float4 c00 = lerp4(q[0], q[1], c.tx);
    float4 c01 = lerp4(q[2], q[3], c.tx);
    float4 c10 = lerp4(q[4], q[5], c.tx);
    float4 c11 = lerp4(q[6], q[7], c.tx);
    float4 c0 = lerp4(c00, c01, c.ty);
    float4 c1 = lerp4(c10, c11, c.ty);
    return lerp4(c0, c1, c.tz);
}

// trilinear for the native-layout 256^3 volume from 16 float2 row-pairs
__device__ __forceinline__ float4 reduce_v3(const float2* qd, const CoordW& c, bool edge) {
    float r[4];
#pragma unroll
    for (int ch = 0; ch < 4; ++ch) {
        float v00a = edge ? qd[ch * 4 + 0].y : qd[ch * 4 + 0].x, v00b = qd[ch * 4 + 0].y;
        float v01a = edge ? qd[ch * 4 + 1].y : qd[ch * 4 + 1].x, v01b = qd[ch * 4 + 1].y;
        float v10a = edge ? qd[ch * 4 + 2].y : qd[ch * 4 + 2].x, v10b = qd[ch * 4 + 2].y;
        float v11a = edge ? qd[ch * 4 + 3].y : qd[ch * 4 + 3].x, v11b = qd[ch * 4 + 3].y;
        float c00 = v00a + (v00b - v00a) * c.tx;
        float c01 = v01a + (v01b - v01a) * c.tx;
        float c10 = v10a + (v10b - v10a) * c.tx;
        float c11 = v11a + (v11b - v11a) * c.tx;
        float e0 = c00 + (c01 - c00) * c.ty;
        float e1 = c10 + (c11 - c10) * c.ty;
        r[ch] = e0 + (e1 - e0) * c.tz;
    }
    return make_float4(r[0], r[1], r[2], r[3]);
}

// ---------------- binning ----------------

__device__ __forceinline__ int bin_of(float gx, float gy, float gz) {
    float ux = fminf(fmaxf((gx + 1.0f) * 0.5f, 0.0f), 1.0f);
    float uy = fminf(fmaxf((gy + 1.0f) * 0.5f, 0.0f), 1.0f);
    float uz = fminf(fmaxf((gz + 1.0f) * 0.5f, 0.0f), 1.0f);
    int bx = min((int)(ux * (float)NB), NB - 1);
    int by = min((int)(uy * (float)NB), NB - 1);
    int bz = min((int)(uz * (float)NB), NB - 1);
    return (bz * NB + by) * NB + bx;
}

// ---------------- fused transpose [C,DHW]->[DHW,C] (3 vols) + histogram ----------------

__global__ __launch_bounds__(256) void xpose_hist_kernel(
    const float* __restrict__ v0, const float* __restrict__ v1, const float* __restrict__ v2,
    float4* __restrict__ w0, float4* __restrict__ w1, float4* __restrict__ w2,
    const float* __restrict__ grid, unsigned* __restrict__ hist)
{
    constexpr int B2 = DHW2 / 256, B1 = DHW1 / 256, B0 = DHW0 / 256;
    int b = blockIdx.x;
    int t = threadIdx.x;
    if (b < B2) {
        int v = b * 256 + t;
        w2[v] = make_float4(v2[v], v2[v + DHW2], v2[v + 2 * DHW2], v2[v + 3 * DHW2]);
    } else if (b < B2 + B1) {
        int v = (b - B2) * 256 + t;
        w1[v] = make_float4(v1[v], v1[v + DHW1], v1[v + 2 * DHW1], v1[v + 3 * DHW1]);
    } else if (b < B2 + B1 + B0) {
        int v = (b - B2 - B1) * 256 + t;
        w0[v] = make_float4(v0[v], v0[v + DHW0], v0[v + 2 * DHW0], v0[v + 3 * DHW0]);
    } else {
        int p = (b - B2 - B1 - B0) * 256 + t;
        float gx = grid[3 * p + 0];
        float gy = grid[3 * p + 1];
        float gz = grid[3 * p + 2];
        atomicAdd(&hist[bin_of(gx, gy, gz)], 1u);
    }
}

// single-workgroup exclusive scan of NBINS=32768 counts (1024 thr x 32 items)
__global__ __launch_bounds__(1024) void scan_kernel(const unsigned* __restrict__ hist,
                                                    unsigned* __restrict__ offsets) {
    __shared__ unsigned partial[1024];
    const int t = threadIdx.x;
    const int base = t * 32;
    unsigned sum = 0;
#pragma unroll
    for (int i = 0; i < 32; ++i) sum += hist[base + i];
    partial[t] = sum;
    __syncthreads();
    for (int off = 1; off < 1024; off <<= 1) {
        unsigned v = (t >= off) ? partial[t - off] : 0u;
        __syncthreads();
        partial[t] += v;
        __syncthreads();
    }
    unsigned run = partial[t] - sum;
#pragma unroll
    for (int i = 0; i < 32; ++i) {
        offsets[base + i] = run;
        run += hist[base + i];
    }
}

// scatter: sorted[pos] = (gx,gy,gz, origP). No inv[] — reordering happens on
// gather's WRITE side.
__global__ __launch_bounds__(256) void scatter_kernel(const float* __restrict__ grid,
                                                      unsigned* __restrict__ offsets,
                                                      float4* __restrict__ sorted) {
    int p = blockIdx.x * blockDim.x + threadIdx.x;
    float gx = grid[3 * p + 0];
    float gy = grid[3 * p + 1];
    float gz = grid[3 * p + 2];
    int b = bin_of(gx, gy, gz);
    unsigned pos = atomicAdd(&offsets[b], 1u);
    sorted[pos] = make_float4(gx, gy, gz, __int_as_float(p));
}

// ---------------- main gather over sorted points (R1 1-pt/thread body) ----------------
// 40 loads issued before any arithmetic (issue order == consume order, v3 last
// so FIFO vmcnt lets f0..f2 math run while v3/HBM loads are in flight).
// Output: one point = one 64B line of wsout (AoS [origP][4]), written by ONE
// thread via 4 consecutive CACHED float4 stores -> TCC merges via byte-enables
// and evicts the line fully-dirty once. R7 measured that NT stores here do NOT
// combine (WRITE 153MB = 2.4x, gather +107us from store-queue backpressure);
// cached is the fix (R2 measured 65.5MB for cached AoS merge).

__global__ __launch_bounds__(256, 3) void gather_sorted_kernel(
    const float4* __restrict__ sorted,
    const float4* __restrict__ w0, const float4* __restrict__ w1,
    const float4* __restrict__ w2, const float* __restrict__ v3,
    float4* __restrict__ wsout)
{
    // XCD swizzle: contiguous sorted range per XCD for L2 locality
    int bid = blockIdx.x;
    int sb = (bid & 7) * (int)(gridDim.x >> 3) + (bid >> 3);
    int s = sb * 256 + (int)threadIdx.x;
    float4 gp = sorted[s];
    float gx = gp.x, gy = gp.y, gz = gp.z;
    int origP = __float_as_int(gp.w);

    CoordW c0 = mkcoord<32>(gx, gy, gz);
    CoordW c1 = mkcoord<64>(gx, gy, gz);
    CoordW c2 = mkcoord<128>(gx, gy, gz);
    CoordW c3 = mkcoord<256>(gx, gy, gz);
    const int  xm = min(c3.x0, 254);
    const bool edge = (c3.x0 == 255);

    float4 qa[8], qb[8], qc[8];
    float2 qd[16];

    qa[0] = w0[c0.b00 + c0.x0]; qa[1] = w0[c0.b00 + c0.x1];
    qa[2] = w0[c0.b01 + c0.x0]; qa[3] = w0[c0.b01 + c0.x1];
    qa[4] = w0[c0.b10 + c0.x0]; qa[5] = w0[c0.b10 + c0.x1];
    qa[6] = w0[c0.b11 + c0.x0]; qa[7] = w0[c0.b11 + c0.x1];

    qb[0] = w1[c1.b00 + c1.x0]; qb[1] = w1[c1.b00 + c1.x1];
    qb[2] = w1[c1.b01 + c1.x0]; qb[3] = w1[c1.b01 + c1.x1];
    qb[4] = w1[c1.b10 + c1.x0]; qb[5] = w1[c1.b10 + c1.x1];
    qb[6] = w1[c1.b11 + c1.x0]; qb[7] = w1[c1.b11 + c1.x1];

    qc[0] = w2[c2.b00 + c2.x0]; qc[1] = w2[c2.b00 + c2.x1];
    qc[2] = w2[c2.b01 + c2.x0]; qc[3] = w2[c2.b01 + c2.x1];
    qc[4] = w2[c2.b10 + c2.x0]; qc[5] = w2[c2.b10 + c2.x1];
    qc[6] = w2[c2.b11 + c2.x0]; qc[7] = w2[c2.b11 + c2.x1];

#pragma unroll
    for (int ch = 0; ch < 4; ++ch) {
        const float* __restrict__ vc = v3 + (size_t)ch * DHW3;
        qd[ch * 4 + 0] = *(const float2*)(vc + c3.b00 + xm);
        qd[ch * 4 + 1] = *(const float2*)(vc + c3.b01 + xm);
        qd[ch * 4 + 2] = *(const float2*)(vc + c3.b10 + xm);
        qd[ch * 4 + 3] = *(const float2*)(vc + c3.b11 + xm);
    }

    __builtin_amdgcn_sched_barrier(0);

    float4 f0 = reduce8(qa, c0);
    float4 f1 = reduce8(qb, c1);
    float4 f2 = reduce8(qc, c2);
    float4 f3 = reduce_v3(qd, c3, edge);

    // cached full-line write (see header comment)
    float4* w = wsout + (size_t)origP * 4;
    w[0] = f0;
    w[1] = f1;
    w[2] = f2;
    w[3] = f3;
}

// ---------------- unpermute: pure streaming pass, fully coalesced both sides --------
// wsout is in ORIGINAL order: read wsout[p][0..3] (contiguous 64B/thread, wave
// reads 16KB linear — also drains the still-LLC-resident gather writes), write
// the 16 SoA output streams (consecutive p across lanes -> full lines).

__global__ __launch_bounds__(256) void unpermute_kernel(const float4* __restrict__ wsout,
                                                        float* __restrict__ out) {
    int p = blockIdx.x * blockDim.x + threadIdx.x;
    const float4* w = wsout + (size_t)p * 4;
    float4 f0 = w[0], f1 = w[1], f2 = w[2], f3 = w[3];
    __builtin_nontemporal_store(f0.x, &out[ 0 * NPTS + p]);
    __builtin_nontemporal_store(f0.y, &out[ 1 * NPTS + p]);
    __builtin_nontemporal_store(f0.z, &out[ 2 * NPTS + p]);
    __builtin_nontemporal_store(f0.w, &out[ 3 * NPTS + p]);
    __builtin_nontemporal_store(f1.x, &out[ 4 * NPTS + p]);
    __builtin_nontemporal_store(f1.y, &out[ 5 * NPTS + p]);
    __builtin_nontemporal_store(f1.z, &out[ 6 * NPTS + p]);
    __builtin_nontemporal_store(f1.w, &out[ 7 * NPTS + p]);
    __builtin_nontemporal_store(f2.x, &out[ 8 * NPTS + p]);
    __builtin_nontemporal_store(f2.y, &out[ 9 * NPTS + p]);
    __builtin_nontemporal_store(f2.z, &out[10 * NPTS + p]);
    __builtin_nontemporal_store(f2.w, &out[11 * NPTS + p]);
    __builtin_nontemporal_store(f3.x, &out[12 * NPTS + p]);
    __builtin_nontemporal_store(f3.y, &out[13 * NPTS + p]);
    __builtin_nontemporal_store(f3.z, &out[14 * NPTS + p]);
    __builtin_nontemporal_store(f3.w, &out[15 * NPTS + p]);
}

// ---------------- fallback paths ----------------

template<int D>
__device__ __forceinline__ float4 sample_inter(const float4* __restrict__ v,
                                               float gx, float gy, float gz) {
    CoordW c = mkcoord<D>(gx, gy, gz);
    float4 q[8];
    q[0] = v[c.b00 + c.x0]; q[1] = v[c.b00 + c.x1];
    q[2] = v[c.b01 + c.x0]; q[3] = v[c.b01 + c.x1];
    q[4] = v[c.b10 + c.x0]; q[5] = v[c.b10 + c.x1];
    q[6] = v[c.b11 + c.x0]; q[7] = v[c.b11 + c.x1];
    return reduce8(q, c);
}

template<int D>
__device__ __forceinline__ float4 sample_direct(const float* __restrict__ v,
                                                float gx, float gy, float gz) {
    CoordW c = mkcoord<D>(gx, gy, gz);
    float r[4];
#pragma unroll
    for (int ch = 0; ch < 4; ++ch) {
        const float* __restrict__ vc = v + (size_t)ch * (D * D * D);
        float c000 = vc[c.b00 + c.x0], c001 = vc[c.b00 + c.x1];
        float c010 = vc[c.b01 + c.x0], c011 = vc[c.b01 + c.x1];
        float c100 = vc[c.b10 + c.x0], c101 = vc[c.b10 + c.x1];
        float c110 = vc[c.b11 + c.x0], c111 = vc[c.b11 + c.x1];
        float c00 = c000 + (c001 - c000) * c.tx;
        float c01 = c010 + (c011 - c010) * c.tx;
        float c10 = c100 + (c101 - c100) * c.tx;
        float c11 = c110 + (c111 - c110) * c.tx;
        float e0 = c00 + (c01 - c00) * c.ty;
        float e1 = c10 + (c11 - c10) * c.ty;
        r[ch] = e0 + (e1 - e0) * c.tz;
    }
    return make_float4(r[0], r[1], r[2], r[3]);
}

__device__ __forceinline__ void store16(const float4 f0, const float4 f1,
                                        const float4 f2, const float4 f3,
                                        float* __restrict__ out, int p) {
    out[ 0 * NPTS + p] = f0.x; out[ 1 * NPTS + p] = f0.y;
    out[ 2 * NPTS + p] = f0.z; out[ 3 * NPTS + p] = f0.w;
    out[ 4 * NPTS + p] = f1.x; out[ 5 * NPTS + p] = f1.y;
    out[ 6 * NPTS + p] = f1.z; out[ 7 * NPTS + p] = f1.w;
    out[ 8 * NPTS + p] = f2.x; out[ 9 * NPTS + p] = f2.y;
    out[10 * NPTS + p] = f2.z; out[11 * NPTS + p] = f2.w;
    out[12 * NPTS + p] = f3.x; out[13 * NPTS + p] = f3.y;
    out[14 * NPTS + p] = f3.z; out[15 * NPTS + p] = f3.w;
}

__global__ __launch_bounds__(256) void mg_direct_kernel(
    const float* __restrict__ grid,
    const float* __restrict__ v0, const float* __restrict__ v1,
    const float* __restrict__ v2, const float* __restrict__ v3,
    float* __restrict__ out)
{
    int p = blockIdx.x * blockDim.x + threadIdx.x;
    float gx = grid[3 * p + 0];
    float gy = grid[3 * p + 1];
    float gz = grid[3 * p + 2];
    float4 f0 = sample_direct<32>(v0, gx, gy, gz);
    float4 f1 = sample_direct<64>(v1, gx, gy, gz);
    float4 f2 = sample_direct<128>(v2, gx, gy, gz);
    float4 f3 = sample_direct<256>(v3, gx, gy, gz);
    store16(f0, f1, f2, f3, out, p);
}

__global__ __launch_bounds__(256) void mg_inter_kernel(
    const float* __restrict__ grid,
    const float4* __restrict__ w0, const float4* __restrict__ w1,
    const float4* __restrict__ w2, const float* __restrict__ v3,
    float* __restrict__ out)
{
    int p = blockIdx.x * blockDim.x + threadIdx.x;
    float gx = grid[3 * p + 0];
    float gy = grid[3 * p + 1];
    float gz = grid[3 * p + 2];
    float4 f0 = sample_inter<32>(w0, gx, gy, gz);
    float4 f1 = sample_inter<64>(w1, gx, gy, gz);
    float4 f2 = sample_inter<128>(w2, gx, gy, gz);
    float4 f3 = sample_direct<256>(v3, gx, gy, gz);
    store16(f0, f1, f2, f3, out, p);
}

// ---------------- launch ----------------

extern "C" void kernel_launch(void* const* d_in, const int* in_sizes, int n_in,
                              void* d_out, int out_size, void* d_ws, size_t ws_size,
                              hipStream_t stream) {
    const float* grid = (const float*)d_in[0];
    const float* v0   = (const float*)d_in[1];   // [4,32,32,32]
    const float* v1   = (const float*)d_in[2];   // [4,64,64,64]
    const float* v2   = (const float*)d_in[3];   // [4,128,128,128]
    const float* v3   = (const float*)d_in[4];   // [4,256,256,256]
    float* out = (float*)d_out;

    // ws layout (bytes)
    constexpr size_t OFF_WSOUT  = 0;                                   // 64 MB (AoS [p][4] float4)
    constexpr size_t OFF_SORTED = OFF_WSOUT  + (size_t)NPTS * 64;      // 16 MB
    constexpr size_t OFF_W2     = OFF_SORTED + (size_t)NPTS * 16;      // 32 MB
    constexpr size_t OFF_W1     = OFF_W2     + (size_t)DHW2 * 16;      // 4 MB
    constexpr size_t OFF_W0     = OFF_W1     + (size_t)DHW1 * 16;      // 0.5 MB
    constexpr size_t OFF_HIST   = OFF_W0     + (size_t)DHW0 * 16;      // 128 KB
    constexpr size_t OFF_OFFS   = OFF_HIST   + (size_t)NBINS * 4;      // 128 KB
    constexpr size_t WS_FULL    = OFF_OFFS   + (size_t)NBINS * 4;      // ~116.8 MB
    constexpr size_t WS_INTER   = (size_t)(DHW0 + DHW1 + DHW2) * 16;   // 36.5 MB

    const int threads = 256;
    const int pt_blocks = NPTS / threads;   // 4096
    char* ws = (char*)d_ws;

    if (ws_size >= WS_FULL) {
        float4*   wsout  = (float4*)(ws + OFF_WSOUT);
        float4*   sorted = (float4*)(ws + OFF_SORTED);
        float4*   w2     = (float4*)(ws + OFF_W2);
        float4*   w1     = (float4*)(ws + OFF_W1);
        float4*   w0     = (float4*)(ws + OFF_W0);
        unsigned* hist   = (unsigned*)(ws + OFF_HIST);
        unsigned* offs   = (unsigned*)(ws + OFF_OFFS);

        (void)hipMemsetAsync(hist, 0, (size_t)NBINS * 4, stream);
        const int xh_blocks = (DHW0 + DHW1 + DHW2) / threads + pt_blocks;
        xpose_hist_kernel<<<xh_blocks, threads, 0, stream>>>(
            v0, v1, v2, w0, w1, w2, grid, hist);
        scan_kernel<<<1, 1024, 0, stream>>>(hist, offs);
        scatter_kernel<<<pt_blocks, threads, 0, stream>>>(grid, offs, sorted);
        gather_sorted_kernel<<<pt_blocks, threads, 0, stream>>>(
            sorted, w0, w1, w2, v3, wsout);
        unpermute_kernel<<<pt_blocks, threads, 0, stream>>>(wsout, out);
    } else if (ws_size >= WS_INTER) {
        float4* w0 = (float4*)d_ws;
        float4* w1 = w0 + DHW0;
        float4* w2 = w1 + DHW1;
        xpose_hist_kernel<<<(DHW0 + DHW1 + DHW2) / threads, threads, 0, stream>>>(
            v0, v1, v2, w0, w1, w2, grid, (unsigned*)nullptr);
        mg_inter_kernel<<<pt_blocks, threads, 0, stream>>>(grid, w0, w1, w2, v3, out);
    } else {
        mg_direct_kernel<<<pt_blocks, threads, 0, stream>>>(grid, v0, v1, v2, v3, out);
    }
}